// Round 16
// baseline (472.331 us; speedup 1.0000x reference)
//
#include <hip/hip_runtime.h>

// SoftRoutedLoRALinear on MI355X — augmented-K f16 MFMA GEMM.
// out[m,n] = sum_k Xa[m,k]*Wa[n,k] + bias[n],  K = 4096 + 128 (LoRA tail)
// Main GEMM: 256x256, BK=32, 8 waves, ring-4 (R15 schedule, compiler-counted
// lgkm) with v_mfma_f32_32x32x16_f16 (20% better MFMA-pipe FLOP/cy, half the
// issue slots) + FRAGMENT-MAJOR LDS (reads = base+lane*16, conflict-free, no
// swizzle; staging pre-permutes the global source, linear gload_lds dest).
// Prep: split-K midk (2048 blocks, f32 atomics) replaces latency-bound mid2.

typedef _Float16 half8 __attribute__((ext_vector_type(8)));
typedef _Float16 half4 __attribute__((ext_vector_type(4)));
typedef float    f32x4  __attribute__((ext_vector_type(4)));
typedef float    f32x16 __attribute__((ext_vector_type(16)));

#define M_TOT 8192
#define N_TOT 4096
#define K_IN  4096
#define KA    4224
#define NT    132     // KA / 32

__device__ __forceinline__ void cvt_store4(_Float16* p, float4 f) {
  half4 h;
  h[0] = (_Float16)f.x; h[1] = (_Float16)f.y;
  h[2] = (_Float16)f.z; h[3] = (_Float16)f.w;
  *(half4*)p = h;
}

// ---------------- prep: f32 -> f16, compile-time source cols
template <int LOG2C, int DCOLS>
__global__ __launch_bounds__(256) void convert_f32_f16_t(
    const float* __restrict__ src, _Float16* __restrict__ dst, int total8) {
  for (int i = blockIdx.x * 256 + threadIdx.x; i < total8;
       i += gridDim.x * 256) {
    int base = i << 3;
    int r = base >> LOG2C;
    int c = base & ((1 << LOG2C) - 1);
    const float4* s = (const float4*)(src + (size_t)base);
    float4 f0 = s[0], f1 = s[1];
    half8 h;
    h[0]=(_Float16)f0.x; h[1]=(_Float16)f0.y; h[2]=(_Float16)f0.z; h[3]=(_Float16)f0.w;
    h[4]=(_Float16)f1.x; h[5]=(_Float16)f1.y; h[6]=(_Float16)f1.z; h[7]=(_Float16)f1.w;
    *(half8*)(dst + (size_t)r * DCOLS + c) = h;
  }
}

// ---------------- prep: lora_B -> Wa tail (f16)
__global__ __launch_bounds__(256) void wtail_gather_f16(
    const float* __restrict__ loraB, _Float16* __restrict__ Wa) {
  int idx = blockIdx.x * 256 + threadIdx.x;
  int n = idx >> 7, j = idx & 127;
  int e = j >> 4, r = j & 15;
  Wa[(size_t)n * KA + K_IN + j] =
      (_Float16)loraB[((size_t)e * N_TOT + n) * 16 + r];
}

// ---------------- prep (fallback): lora_B -> fp32 [4096][128]
__global__ __launch_bounds__(256) void lorabf_gather_f32(
    const float* __restrict__ loraB, float* __restrict__ lorabf) {
  int idx = blockIdx.x * 256 + threadIdx.x;
  int n = idx >> 7, j = idx & 127;
  int e = j >> 4, r = j & 15;
  lorabf[(size_t)n * 128 + j] = loraB[((size_t)e * N_TOT + n) * 16 + r];
}

// ---------------- zero helper (midw init each call — ws is not re-poisoned)
__global__ __launch_bounds__(256) void zero_f4(float4* p, int n) {
  int i = blockIdx.x * 256 + threadIdx.x;
  if (i < n) { float4 z = {0.f, 0.f, 0.f, 0.f}; p[i] = z; }
}

// ---------------- split-K mid: partial x @ loraA^T -> atomicAdd f32 midw
// grid 2048: (bid>>3) = 32-row m-block; (bid&7) = K-slice of 512 (8 x K64).
__global__ __launch_bounds__(256) void midk_kernel(
    const float* __restrict__ x, const float* __restrict__ loraA,
    float* __restrict__ midw) {
  __shared__ _Float16 As[32 * 64];
  __shared__ _Float16 Bs[128 * 64];
  int tid = threadIdx.x, lane = tid & 63, w = tid >> 6;
  int m0 = (blockIdx.x >> 3) * 32;
  int ks0 = (blockIdx.x & 7) * 8;
  f32x4 acc[2][2] = {};
  for (int ks = ks0; ks < ks0 + 8; ++ks) {
    int k0 = ks * 64;
#pragma unroll
    for (int it = 0; it < 2; ++it) {
      int idx = tid + it * 256;
      int r = idx >> 4, c4 = idx & 15;
      float4 f = *(const float4*)(x + (size_t)(m0 + r) * K_IN + k0 + c4 * 4);
      cvt_store4(As + r * 64 + c4 * 4, f);
    }
#pragma unroll
    for (int it = 0; it < 8; ++it) {
      int idx = tid + it * 256;
      int r = idx >> 4, c4 = idx & 15;
      float4 f = *(const float4*)(loraA + (size_t)r * K_IN + k0 + c4 * 4);
      cvt_store4(Bs + r * 64 + c4 * 4, f);
    }
    __syncthreads();
#pragma unroll
    for (int kk = 0; kk < 2; ++kk) {
      half8 a[2], bf[2];
#pragma unroll
      for (int mi = 0; mi < 2; ++mi)
        a[mi] = *(const half8*)(As + (mi * 16 + (lane & 15)) * 64 + kk * 32 + (lane >> 4) * 8);
#pragma unroll
      for (int ni = 0; ni < 2; ++ni)
        bf[ni] = *(const half8*)(Bs + (w * 32 + ni * 16 + (lane & 15)) * 64 + kk * 32 + (lane >> 4) * 8);
#pragma unroll
      for (int mi = 0; mi < 2; ++mi)
#pragma unroll
        for (int ni = 0; ni < 2; ++ni)
          acc[mi][ni] = __builtin_amdgcn_mfma_f32_16x16x32_f16(a[mi], bf[ni], acc[mi][ni], 0, 0, 0);
    }
    __syncthreads();
  }
#pragma unroll
  for (int ni = 0; ni < 2; ++ni) {
    int j = w * 32 + ni * 16 + (lane & 15);
#pragma unroll
    for (int mi = 0; mi < 2; ++mi) {
      f32x4 v = acc[mi][ni];
#pragma unroll
      for (int jj = 0; jj < 4; ++jj) {
        int m = m0 + mi * 16 + (lane >> 4) * 4 + jj;
        atomicAdd(&midw[(size_t)m * 128 + j], v[jj]);
      }
    }
  }
}

// ---------------- scale by router and pack f16 into Xa tail
__global__ __launch_bounds__(256) void scale_pack(
    const float* __restrict__ midw, const float* __restrict__ router,
    _Float16* __restrict__ Xa) {
  int idx = blockIdx.x * 256 + threadIdx.x;   // < 8192*128
  int m = idx >> 7, j = idx & 127;
  int b = m >> 11, e = j >> 4;
  Xa[(size_t)m * KA + K_IN + j] = (_Float16)(2.0f * router[b * 8 + e] * midw[idx]);
}

// ---------------- middle-path mid (reads f16 Xa + f16 loraA) — R12 version
__global__ __launch_bounds__(256) void mid2_kernel(
    _Float16* __restrict__ Xa, const _Float16* __restrict__ lAh,
    const float* __restrict__ router) {
  __shared__ _Float16 As[32 * 64];
  __shared__ _Float16 Bs[128 * 64];
  int tid = threadIdx.x, lane = tid & 63, w = tid >> 6;
  int m0 = blockIdx.x * 32;
  int b = m0 >> 11;
  f32x4 acc[2][2] = {};
  int scol = ((lane & 7) ^ (lane >> 3)) * 16;
  int ln15 = lane & 15, ln4 = lane >> 4;
  for (int ks = 0; ks < 64; ++ks) {
    int kb = ks * 128;
    {
      const char* s = (const char*)Xa +
          (size_t)(m0 + w * 8 + (lane >> 3)) * (KA * 2) + kb + scol;
      __builtin_amdgcn_global_load_lds(
          (const __attribute__((address_space(1))) void*)s,
          (__attribute__((address_space(3))) void*)((char*)As + w * 1024 + lane * 16), 16, 0, 0);
    }
#pragma unroll
    for (int i = 0; i < 4; ++i) {
      const char* s = (const char*)lAh +
          (size_t)((w * 4 + i) * 8 + (lane >> 3)) * (4096 * 2) + kb + scol;
      __builtin_amdgcn_global_load_lds(
          (const __attribute__((address_space(1))) void*)s,
          (__attribute__((address_space(3))) void*)((char*)Bs + (w * 4 + i) * 1024 + lane * 16), 16, 0, 0);
    }
    __syncthreads();
#pragma unroll
    for (int kk = 0; kk < 2; ++kk) {
      int rs = (((kk * 4 + ln4) ^ (ln15 & 7)) << 4);
      half8 a[2], bf[2];
#pragma unroll
      for (int mi = 0; mi < 2; ++mi)
        a[mi] = *(const half8*)((const char*)As + (mi * 16 + ln15) * 128 + rs);
#pragma unroll
      for (int ni = 0; ni < 2; ++ni)
        bf[ni] = *(const half8*)((const char*)Bs + (w * 32 + ni * 16 + ln15) * 128 + rs);
#pragma unroll
      for (int mi = 0; mi < 2; ++mi)
#pragma unroll
        for (int ni = 0; ni < 2; ++ni)
          acc[mi][ni] = __builtin_amdgcn_mfma_f32_16x16x32_f16(a[mi], bf[ni], acc[mi][ni], 0, 0, 0);
    }
    __syncthreads();
  }
#pragma unroll
  for (int ni = 0; ni < 2; ++ni) {
    int j = w * 32 + ni * 16 + ln15;
    int e = j >> 4;
    float sc = 2.0f * router[b * 8 + e];
#pragma unroll
    for (int mi = 0; mi < 2; ++mi) {
      f32x4 v = acc[mi][ni];
#pragma unroll
      for (int jj = 0; jj < 4; ++jj) {
        int m = m0 + mi * 16 + ln4 * 4 + jj;
        Xa[(size_t)m * KA + K_IN + j] = (_Float16)(v[jj] * sc);
      }
    }
  }
}

// ---------------- fallback mid (f32 sources -> f32 midw, router fused)
__global__ __launch_bounds__(256) void mid_kernel(
    const float* __restrict__ x, const float* __restrict__ loraA,
    const float* __restrict__ router, float* __restrict__ midw) {
  __shared__ _Float16 As[32 * 64];
  __shared__ _Float16 Bs[128 * 64];
  int tid = threadIdx.x, lane = tid & 63, w = tid >> 6;
  int m0 = blockIdx.x * 32;
  int b = m0 >> 11;
  f32x4 acc[2][2] = {};
  for (int ks = 0; ks < 64; ++ks) {
    int k0 = ks * 64;
#pragma unroll
    for (int it = 0; it < 2; ++it) {
      int idx = tid + it * 256;
      int r = idx >> 4, c4 = idx & 15;
      float4 f = *(const float4*)(x + (size_t)(m0 + r) * K_IN + k0 + c4 * 4);
      cvt_store4(As + r * 64 + c4 * 4, f);
    }
#pragma unroll
    for (int it = 0; it < 8; ++it) {
      int idx = tid + it * 256;
      int r = idx >> 4, c4 = idx & 15;
      float4 f = *(const float4*)(loraA + (size_t)r * K_IN + k0 + c4 * 4);
      cvt_store4(Bs + r * 64 + c4 * 4, f);
    }
    __syncthreads();
#pragma unroll
    for (int kk = 0; kk < 2; ++kk) {
      half8 a[2], bf[2];
#pragma unroll
      for (int mi = 0; mi < 2; ++mi)
        a[mi] = *(const half8*)(As + (mi * 16 + (lane & 15)) * 64 + kk * 32 + (lane >> 4) * 8);
#pragma unroll
      for (int ni = 0; ni < 2; ++ni)
        bf[ni] = *(const half8*)(Bs + (w * 32 + ni * 16 + (lane & 15)) * 64 + kk * 32 + (lane >> 4) * 8);
#pragma unroll
      for (int mi = 0; mi < 2; ++mi)
#pragma unroll
        for (int ni = 0; ni < 2; ++ni)
          acc[mi][ni] = __builtin_amdgcn_mfma_f32_16x16x32_f16(a[mi], bf[ni], acc[mi][ni], 0, 0, 0);
    }
    __syncthreads();
  }
#pragma unroll
  for (int ni = 0; ni < 2; ++ni) {
    int j = w * 32 + ni * 16 + (lane & 15);
    int e = j >> 4;
    float sc = 2.0f * router[b * 8 + e];
#pragma unroll
    for (int mi = 0; mi < 2; ++mi) {
      f32x4 v = acc[mi][ni];
#pragma unroll
      for (int jj = 0; jj < 4; ++jj) {
        int m = m0 + mi * 16 + (lane >> 4) * 4 + jj;
        midw[(size_t)m * 128 + j] = v[jj] * sc;
      }
    }
  }
}

// ====== main GEMM: 256x256, BK=32, ring-4, 32x32x16 MFMA, fragment-major ====
#define BAR    __builtin_amdgcn_s_barrier()
#define SCHED0 __builtin_amdgcn_sched_barrier(0)
#define VMW8   asm volatile("s_waitcnt vmcnt(8)" ::: "memory")
#define VMW4   asm volatile("s_waitcnt vmcnt(4)" ::: "memory")
#define VMW0   asm volatile("s_waitcnt vmcnt(0)" ::: "memory")
#define GLOAD(src, dst) __builtin_amdgcn_global_load_lds( \
    (const __attribute__((address_space(1))) void*)(src), \
    (__attribute__((address_space(3))) void*)(dst), 16, 0, 0)

// LDS: A ring slot SL at [SL*16384); B at 65536 + SL*16384.
// Fragment-major: chunk c = (blk32)*2 + khalf, 1KB each, element = lane*16.
// B read first: first MFMA (aF[0][0] x bF[0][0]) depends on reads 1 and 5;
// compiler-counted lgkm drains the rest under the MFMA burst.
#define READS(SL) do { \
  _Pragma("unroll") for (int ni = 0; ni < 2; ++ni) \
    _Pragma("unroll") for (int kk = 0; kk < 2; ++kk) \
      bF[ni][kk] = *(const half8*)(LDS + 65536 + (SL) * 16384 + \
                                   (((nbB + ni) * 2 + kk) << 10) + lane * 16); \
  _Pragma("unroll") for (int mi = 0; mi < 4; ++mi) \
    _Pragma("unroll") for (int kk = 0; kk < 2; ++kk) \
      aF[mi][kk] = *(const half8*)(LDS + (SL) * 16384 + \
                                   (((mbB + mi) * 2 + kk) << 10) + lane * 16); \
  } while (0)

// stage K32-tile TT into ring slot SL (A:2 + B:2 gloads, linear LDS dest,
// fragment-major via pre-permuted global source offsets)
#define STAGE4(TT, SL) do { \
  const char* sA_ = XpC + (size_t)(TT) * 64; \
  const char* sB_ = WpC + (size_t)(TT) * 64; \
  GLOAD(sA_ + goffA[0], LDS + (SL) * 16384 + lof[0]); \
  GLOAD(sA_ + goffA[1], LDS + (SL) * 16384 + lof[1]); \
  GLOAD(sB_ + goffA[0], LDS + 65536 + (SL) * 16384 + lof[0]); \
  GLOAD(sB_ + goffA[1], LDS + 65536 + (SL) * 16384 + lof[1]); \
  } while (0)

#define MFMA16X do { \
  _Pragma("unroll") for (int mi = 0; mi < 4; ++mi) \
    _Pragma("unroll") for (int ni = 0; ni < 2; ++ni) \
      _Pragma("unroll") for (int kk = 0; kk < 2; ++kk) \
        acc[mi][ni] = __builtin_amdgcn_mfma_f32_32x32x16_f16( \
            aF[mi][kk], bF[ni][kk], acc[mi][ni], 0, 0, 0); \
  } while (0)

#define TILE_FULL(SL) do { \
  READS(SL); \
  STAGE4(t4 + (SL) + 3, ((SL) + 3) & 3); \
  MFMA16X; VMW8; BAR; SCHED0; \
  } while (0)

__global__ __launch_bounds__(512, 2) void gemm256(
    const _Float16* __restrict__ Xa, const _Float16* __restrict__ Wa,
    const float* __restrict__ bias, float* __restrict__ out) {
  __shared__ __align__(16) char LDS[131072];

  int tid = threadIdx.x, lane = tid & 63, w = tid >> 6;
  int mbB = (w >> 2) * 4;   // 32-row block base (wave covers 128 rows)
  int nbB = (w & 3) * 2;    // 32-col block base (wave covers 64 cols)

  // T1: XCD chunk swizzle — 512 blocks = 8 XCDs x 64; each XCD an 8x8 chunk.
  int bid = blockIdx.x;
  int xcd = bid & 7, idx = bid >> 3;
  int mt = (xcd & 3) * 8 + (idx & 7);
  int nt = (xcd >> 2) * 8 + (idx >> 3);
  int m0 = mt << 8, n0 = nt << 8;

  const char* XpC = (const char*)Xa + (size_t)m0 * (KA * 2);
  const char* WpC = (const char*)Wa + (size_t)n0 * (KA * 2);

  // Fragment-major staging: linear LDS idx -> (chunk, lane'); global source
  // row = (c>>1)*32 + (l'&31), kbyte = (c&1)*32 + (l'>>5)*16.
  int goffA[2], lof[2];
#pragma unroll
  for (int j = 0; j < 2; ++j) {
    int ix = j * 512 + tid;
    int c = ix >> 6, lp = ix & 63;
    int row = (c >> 1) * 32 + (lp & 31);
    int kb = ((c & 1) << 5) + ((lp >> 5) << 4);
    goffA[j] = row * (KA * 2) + kb;
    lof[j] = ix * 16;
  }

  f32x16 acc[4][2] = {};
  half8 aF[4][2], bF[2][2];

  // prologue: stage ring slots 0,1,2 (tiles 0,1,2); drain tile 0; publish.
  STAGE4(0, 0); STAGE4(1, 1); STAGE4(2, 2);
  VMW8; BAR; SCHED0;

  // steady state: t = 0..127 (all stage t+3, guard vmcnt(8))
#pragma unroll 1
  for (int t4 = 0; t4 < NT - 4; t4 += 4) {
    TILE_FULL(0); TILE_FULL(1); TILE_FULL(2); TILE_FULL(3);
  }

  // peeled tail t = 128..131 (ring slots 0..3)
  { READS(0); STAGE4(131, 3); MFMA16X; VMW8; BAR; SCHED0; }  // t=128
  { READS(1); MFMA16X; VMW4; BAR; SCHED0; }                  // t=129
  { READS(2); MFMA16X; VMW0; BAR; SCHED0; }                  // t=130
  { READS(3); MFMA16X; }                                     // t=131

  // epilogue: + bias, fp32 store.
  // C/D 32x32: col = lane&31, row = (reg&3) + 8*(reg>>2) + 4*(lane>>5).
#pragma unroll
  for (int ni = 0; ni < 2; ++ni) {
    int n = n0 + (nbB + ni) * 32 + (lane & 31);
    float bz = bias[n];
#pragma unroll
    for (int mi = 0; mi < 4; ++mi) {
      f32x16 v = acc[mi][ni];
      int rb = m0 + (mbB + mi) * 32 + ((lane >> 5) << 2);
#pragma unroll
      for (int reg = 0; reg < 16; ++reg) {
        int r = rb + (reg & 3) + ((reg >> 2) << 3);
        out[(size_t)r * N_TOT + n] = v[reg] + bz;
      }
    }
  }
}

// ---------------- fallback GEMM (reg-staged f32->f16, 128x128, low ws)
__global__ __launch_bounds__(256) void gemm_fallback(
    const float* __restrict__ x, const float* __restrict__ wgt,
    const float* __restrict__ midw, const float* __restrict__ lorabf,
    const float* __restrict__ bias, float* __restrict__ out) {
  __shared__ _Float16 As[128 * 64];
  __shared__ _Float16 Bs[128 * 64];
  int tid = threadIdx.x, lane = tid & 63, w = tid >> 6;
  int mt = blockIdx.x & 63, nt = blockIdx.x >> 6;
  int m0 = mt << 7, n0 = nt << 7;
  int wm = (w >> 1) * 64, wn = (w & 1) * 64;
  f32x4 acc[4][4] = {};
  for (int ks = 0; ks < 66; ++ks) {
    int k0 = ks * 64;
    const float *asrc, *bsrc; size_t astr, bstr; int ac, bc;
    if (ks < 64) { asrc = x;    astr = K_IN; ac = k0;        bsrc = wgt;    bstr = K_IN; bc = k0; }
    else         { asrc = midw; astr = 128;  ac = k0 - K_IN; bsrc = lorabf; bstr = 128;  bc = k0 - K_IN; }
#pragma unroll
    for (int it = 0; it < 8; ++it) {
      int idx = tid + it * 256;
      int r = idx >> 4, c4 = idx & 15;
      float4 fa = *(const float4*)(asrc + (size_t)(m0 + r) * astr + ac + c4 * 4);
      cvt_store4(As + r * 64 + c4 * 4, fa);
      float4 fb = *(const float4*)(bsrc + (size_t)(n0 + r) * bstr + bc + c4 * 4);
      cvt_store4(Bs + r * 64 + c4 * 4, fb);
    }
    __syncthreads();
#pragma unroll
    for (int kk = 0; kk < 2; ++kk) {
      half8 a[4], bf[4];
#pragma unroll
      for (int mi = 0; mi < 4; ++mi)
        a[mi] = *(const half8*)(As + (wm + mi * 16 + (lane & 15)) * 64 + kk * 32 + (lane >> 4) * 8);
#pragma unroll
      for (int ni = 0; ni < 4; ++ni)
        bf[ni] = *(const half8*)(Bs + (wn + ni * 16 + (lane & 15)) * 64 + kk * 32 + (lane >> 4) * 8);
#pragma unroll
      for (int mi = 0; mi < 4; ++mi)
#pragma unroll
        for (int ni = 0; ni < 4; ++ni)
          acc[mi][ni] = __builtin_amdgcn_mfma_f32_16x16x32_f16(a[mi], bf[ni], acc[mi][ni], 0, 0, 0);
    }
    __syncthreads();
  }
#pragma unroll
  for (int ni = 0; ni < 4; ++ni) {
    int n = n0 + wn + ni * 16 + (lane & 15);
    float bz = bias[n];
#pragma unroll
    for (int mi = 0; mi < 4; ++mi) {
      f32x4 v = acc[mi][ni];
      int mbase = m0 + wm + mi * 16 + (lane >> 4) * 4;
#pragma unroll
      for (int jj = 0; jj < 4; ++jj)
        out[(size_t)(mbase + jj) * N_TOT + n] = v[jj] + bz;
    }
  }
}

extern "C" void kernel_launch(void* const* d_in, const int* in_sizes, int n_in,
                              void* d_out, int out_size, void* d_ws, size_t ws_size,
                              hipStream_t stream) {
  const float* x      = (const float*)d_in[0];
  const float* router = (const float*)d_in[1];
  const float* wgt    = (const float*)d_in[2];
  const float* bias   = (const float*)d_in[3];
  const float* loraA  = (const float*)d_in[4];
  const float* loraB  = (const float*)d_in[5];
  float* out = (float*)d_out;
  char* ws = (char*)d_ws;

  const size_t XAUG_B = (size_t)M_TOT * KA * 2;    // 69,206,016
  const size_t WAUG_B = (size_t)N_TOT * KA * 2;    // 34,603,008
  const size_t LAH_B  = (size_t)128 * K_IN * 2;    //  1,048,576
  const size_t MIDW_B = (size_t)M_TOT * 128 * 4;   //  4,194,304
  const size_t MIDF_B = MIDW_B;

  if (ws_size >= XAUG_B + WAUG_B + MIDW_B) {
    // new fast path: split-K mid
    _Float16* Xa  = (_Float16*)ws;
    _Float16* Wa  = (_Float16*)(ws + XAUG_B);
    float* midw   = (float*)(ws + XAUG_B + WAUG_B);
    convert_f32_f16_t<12, KA><<<2048, 256, 0, stream>>>(x,   Xa, M_TOT * K_IN / 8);
    convert_f32_f16_t<12, KA><<<2048, 256, 0, stream>>>(wgt, Wa, N_TOT * K_IN / 8);
    wtail_gather_f16<<<2048, 256, 0, stream>>>(loraB, Wa);
    zero_f4<<<1024, 256, 0, stream>>>((float4*)midw, M_TOT * 128 / 4);
    midk_kernel<<<2048, 256, 0, stream>>>(x, loraA, midw);
    scale_pack<<<4096, 256, 0, stream>>>(midw, router, Xa);
    gemm256<<<512, 512, 0, stream>>>(Xa, Wa, bias, out);
  } else if (ws_size >= XAUG_B + WAUG_B + LAH_B) {
    // middle path: old mid2 (needs only 1MB extra)
    _Float16* Xa  = (_Float16*)ws;
    _Float16* Wa  = (_Float16*)(ws + XAUG_B);
    _Float16* lAh = (_Float16*)(ws + XAUG_B + WAUG_B);
    convert_f32_f16_t<12, KA><<<2048, 256, 0, stream>>>(x,   Xa, M_TOT * K_IN / 8);
    convert_f32_f16_t<12, KA><<<2048, 256, 0, stream>>>(wgt, Wa, N_TOT * K_IN / 8);
    convert_f32_f16_t<12, 4096><<<256, 256, 0, stream>>>(loraA, lAh, 128 * K_IN / 8);
    wtail_gather_f16<<<2048, 256, 0, stream>>>(loraB, Wa);
    mid2_kernel<<<256, 256, 0, stream>>>(Xa, lAh, router);
    gemm256<<<512, 512, 0, stream>>>(Xa, Wa, bias, out);
  } else {
    float* midw   = (float*)ws;
    float* lorabf = (float*)(ws + MIDF_B);
    lorabf_gather_f32<<<2048, 256, 0, stream>>>(loraB, lorabf);
    mid_kernel<<<256, 256, 0, stream>>>(x, loraA, router, midw);
    gemm_fallback<<<2048, 256, 0, stream>>>(x, wgt, midw, lorabf, bias, out);
  }
}

// Round 17
// 405.876 us; speedup vs baseline: 1.1637x; 1.1637x over previous
//
#include <hip/hip_runtime.h>

// SoftRoutedLoRALinear on MI355X — augmented-K f16 MFMA GEMM.
// out[m,n] = sum_k Xa[m,k]*Wa[n,k] + bias[n],  K = 4096 + 128 (LoRA tail)
//   Xa tail[m, e*16+r] = 2*router[b,e] * sum_i x[m,i]*lora_A[e,r,i]
//   Wa tail[n, e*16+r] = lora_B[e,n,r]
// Main GEMM: R15 ring-4 (best: 260us, MfmaUtil 53, serial LDS+MFMA floor).
// Prep: mid3 = LDS-free, barrier-free x@loraA^T (direct-global fragments,
// lAh L2-resident, unrolled; replaces the latency-bound mid2 ~50us).

typedef _Float16 half8 __attribute__((ext_vector_type(8)));
typedef _Float16 half4 __attribute__((ext_vector_type(4)));
typedef float    f32x4 __attribute__((ext_vector_type(4)));

#define M_TOT 8192
#define N_TOT 4096
#define K_IN  4096
#define KA    4224
#define NT    132     // KA / 32

__device__ __forceinline__ void cvt_store4(_Float16* p, float4 f) {
  half4 h;
  h[0] = (_Float16)f.x; h[1] = (_Float16)f.y;
  h[2] = (_Float16)f.z; h[3] = (_Float16)f.w;
  *(half4*)p = h;
}

// ---------------- prep: f32 -> f16, compile-time source cols (no runtime div)
template <int LOG2C, int DCOLS>
__global__ __launch_bounds__(256) void convert_f32_f16_t(
    const float* __restrict__ src, _Float16* __restrict__ dst, int total8) {
  for (int i = blockIdx.x * 256 + threadIdx.x; i < total8;
       i += gridDim.x * 256) {
    int base = i << 3;
    int r = base >> LOG2C;
    int c = base & ((1 << LOG2C) - 1);
    const float4* s = (const float4*)(src + (size_t)base);
    float4 f0 = s[0], f1 = s[1];
    half8 h;
    h[0]=(_Float16)f0.x; h[1]=(_Float16)f0.y; h[2]=(_Float16)f0.z; h[3]=(_Float16)f0.w;
    h[4]=(_Float16)f1.x; h[5]=(_Float16)f1.y; h[6]=(_Float16)f1.z; h[7]=(_Float16)f1.w;
    *(half8*)(dst + (size_t)r * DCOLS + c) = h;
  }
}

// ---------------- prep: lora_B -> Wa tail (f16)
__global__ __launch_bounds__(256) void wtail_gather_f16(
    const float* __restrict__ loraB, _Float16* __restrict__ Wa) {
  int idx = blockIdx.x * 256 + threadIdx.x;       // 0 .. 4096*128-1
  int n = idx >> 7, j = idx & 127;
  int e = j >> 4, r = j & 15;
  Wa[(size_t)n * KA + K_IN + j] =
      (_Float16)loraB[((size_t)e * N_TOT + n) * 16 + r];
}

// ---------------- prep (fallback): lora_B -> fp32 [4096][128]
__global__ __launch_bounds__(256) void lorabf_gather_f32(
    const float* __restrict__ loraB, float* __restrict__ lorabf) {
  int idx = blockIdx.x * 256 + threadIdx.x;
  int n = idx >> 7, j = idx & 127;
  int e = j >> 4, r = j & 15;
  lorabf[(size_t)n * 128 + j] = loraB[((size_t)e * N_TOT + n) * 16 + r];
}

// ---------------- mid3: LDS-free, barrier-free x@loraA^T -> Xa tail
// 512 blocks x 256 thr; block = 16 m-rows; wave w handles cols w*32..w*32+31.
// Per K32 step: 1 A-frag (Xa, global) + 2 B-frags (lAh, L2-resident).
__global__ __launch_bounds__(256) void mid3_kernel(
    _Float16* __restrict__ Xa, const _Float16* __restrict__ lAh,
    const float* __restrict__ router) {
  int tid = threadIdx.x, lane = tid & 63, w = tid >> 6;
  int ln15 = lane & 15, ln4 = lane >> 4;
  int m0 = blockIdx.x * 16;
  int b = m0 >> 11;

  const char* aB = (const char*)Xa + (size_t)(m0 + ln15) * (KA * 2) + ln4 * 16;
  const char* bB0 = (const char*)lAh +
      (size_t)(w * 32 + 0 * 16 + ln15) * (K_IN * 2) + ln4 * 16;
  const char* bB1 = (const char*)lAh +
      (size_t)(w * 32 + 1 * 16 + ln15) * (K_IN * 2) + ln4 * 16;

  f32x4 acc[2] = {};
#pragma unroll 4
  for (int ks = 0; ks < 128; ++ks) {
    half8 a  = *(const half8*)(aB  + ks * 64);
    half8 b0 = *(const half8*)(bB0 + ks * 64);
    half8 b1 = *(const half8*)(bB1 + ks * 64);
    acc[0] = __builtin_amdgcn_mfma_f32_16x16x32_f16(a, b0, acc[0], 0, 0, 0);
    acc[1] = __builtin_amdgcn_mfma_f32_16x16x32_f16(a, b1, acc[1], 0, 0, 0);
  }

#pragma unroll
  for (int ni = 0; ni < 2; ++ni) {
    int j = w * 32 + ni * 16 + ln15;
    int e = j >> 4;
    float sc = 2.0f * router[b * 8 + e];
    f32x4 v = acc[ni];
#pragma unroll
    for (int jj = 0; jj < 4; ++jj) {
      int m = m0 + ln4 * 4 + jj;
      Xa[(size_t)m * KA + K_IN + j] = (_Float16)(v[jj] * sc);
    }
  }
}

// ---------------- fallback mid (f32 sources -> f32 midw, router fused)
__global__ __launch_bounds__(256) void mid_kernel(
    const float* __restrict__ x, const float* __restrict__ loraA,
    const float* __restrict__ router, float* __restrict__ midw) {
  __shared__ _Float16 As[32 * 64];
  __shared__ _Float16 Bs[128 * 64];
  int tid = threadIdx.x, lane = tid & 63, w = tid >> 6;
  int m0 = blockIdx.x * 32;
  int b = m0 >> 11;
  f32x4 acc[2][2] = {};
  for (int ks = 0; ks < 64; ++ks) {
    int k0 = ks * 64;
#pragma unroll
    for (int it = 0; it < 2; ++it) {
      int idx = tid + it * 256;
      int r = idx >> 4, c4 = idx & 15;
      float4 f = *(const float4*)(x + (size_t)(m0 + r) * K_IN + k0 + c4 * 4);
      cvt_store4(As + r * 64 + c4 * 4, f);
    }
#pragma unroll
    for (int it = 0; it < 8; ++it) {
      int idx = tid + it * 256;
      int r = idx >> 4, c4 = idx & 15;
      float4 f = *(const float4*)(loraA + (size_t)r * K_IN + k0 + c4 * 4);
      cvt_store4(Bs + r * 64 + c4 * 4, f);
    }
    __syncthreads();
#pragma unroll
    for (int kk = 0; kk < 2; ++kk) {
      half8 a[2], bf[2];
#pragma unroll
      for (int mi = 0; mi < 2; ++mi)
        a[mi] = *(const half8*)(As + (mi * 16 + (lane & 15)) * 64 + kk * 32 + (lane >> 4) * 8);
#pragma unroll
      for (int ni = 0; ni < 2; ++ni)
        bf[ni] = *(const half8*)(Bs + (w * 32 + ni * 16 + (lane & 15)) * 64 + kk * 32 + (lane >> 4) * 8);
#pragma unroll
      for (int mi = 0; mi < 2; ++mi)
#pragma unroll
        for (int ni = 0; ni < 2; ++ni)
          acc[mi][ni] = __builtin_amdgcn_mfma_f32_16x16x32_f16(a[mi], bf[ni], acc[mi][ni], 0, 0, 0);
    }
    __syncthreads();
  }
#pragma unroll
  for (int ni = 0; ni < 2; ++ni) {
    int j = w * 32 + ni * 16 + (lane & 15);
    int e = j >> 4;
    float sc = 2.0f * router[b * 8 + e];
#pragma unroll
    for (int mi = 0; mi < 2; ++mi) {
      f32x4 v = acc[mi][ni];
#pragma unroll
      for (int jj = 0; jj < 4; ++jj) {
        int m = m0 + mi * 16 + (lane >> 4) * 4 + jj;
        midw[(size_t)m * 128 + j] = v[jj] * sc;
      }
    }
  }
}

// ====== main GEMM: 256x256, BK=32, 8 waves, ring-4, compiler-counted lgkm ===
#define BAR    __builtin_amdgcn_s_barrier()
#define SCHED0 __builtin_amdgcn_sched_barrier(0)
#define VMW8   asm volatile("s_waitcnt vmcnt(8)" ::: "memory")
#define VMW4   asm volatile("s_waitcnt vmcnt(4)" ::: "memory")
#define VMW0   asm volatile("s_waitcnt vmcnt(0)" ::: "memory")
#define GLOAD(src, dst) __builtin_amdgcn_global_load_lds( \
    (const __attribute__((address_space(1))) void*)(src), \
    (__attribute__((address_space(3))) void*)(dst), 16, 0, 0)

// A slot SL at LDS bytes [SL*16384, +16K); B at 65536 + SL*16384.
// B read FIRST so the first MFMA (aF[0] x bF[0..3]) depends on reads 1-5;
// the compiler's counted lgkmcnt lets reads 6-12 drain under the MFMA burst.
#define READS(SL) do { \
  _Pragma("unroll") for (int ni = 0; ni < 4; ++ni) \
    bF[ni] = *(const half8*)(LDS + 65536 + (SL) * 16384 + \
                             (wn + ni * 16 + ln15) * 64 + rslot); \
  _Pragma("unroll") for (int mi = 0; mi < 8; ++mi) \
    aF[mi] = *(const half8*)(LDS + (SL) * 16384 + \
                             (wm + mi * 16 + ln15) * 64 + rslot); \
  } while (0)

// stage K32-tile TT into ring slot SL (A:2 + B:2 gloads, linear LDS dest)
#define STAGE4(TT, SL) do { \
  const char* sA_ = XpC + (size_t)(TT) * 64; \
  const char* sB_ = WpC + (size_t)(TT) * 64; \
  GLOAD(sA_ + goff0, LDS + (SL) * 16384 + l0); \
  GLOAD(sA_ + goff1, LDS + (SL) * 16384 + l1); \
  GLOAD(sB_ + goff0, LDS + 65536 + (SL) * 16384 + l0); \
  GLOAD(sB_ + goff1, LDS + 65536 + (SL) * 16384 + l1); \
  } while (0)

#define MFMA32 do { \
  _Pragma("unroll") for (int mi = 0; mi < 8; ++mi) \
    _Pragma("unroll") for (int ni = 0; ni < 4; ++ni) \
      acc[mi][ni] = __builtin_amdgcn_mfma_f32_16x16x32_f16( \
          aF[mi], bF[ni], acc[mi][ni], 0, 0, 0); \
  } while (0)

// steady tile: NO explicit lgkm drain — compiler-counted waits interleave
// read-drain with the MFMA burst. vmcnt(8) ring guard unchanged (drains t+1,
// staged 3 tiles ago; barrier publishes + separates WAR on slot (SL+3)&3).
#define TILE_FULL(SL) do { \
  READS(SL); \
  STAGE4(t4 + (SL) + 3, ((SL) + 3) & 3); \
  MFMA32; VMW8; BAR; SCHED0; \
  } while (0)

__global__ __launch_bounds__(512, 2) void gemm256(
    const _Float16* __restrict__ Xa, const _Float16* __restrict__ Wa,
    const float* __restrict__ bias, float* __restrict__ out) {
  __shared__ __align__(16) char LDS[131072];   // A ring 64K | B ring 64K

  int tid = threadIdx.x, lane = tid & 63, w = tid >> 6;
  int ln15 = lane & 15, ln4 = lane >> 4;
  int wm = (w >> 2) * 128, wn = (w & 3) * 64;

  // T1: XCD chunk swizzle — 512 blocks = 8 XCDs x 64; each XCD an 8x8 chunk.
  int bid = blockIdx.x;
  int xcd = bid & 7, idx = bid >> 3;
  int mt = (xcd & 3) * 8 + (idx & 7);
  int nt = (xcd >> 2) * 8 + (idx >> 3);
  int m0 = mt << 8, n0 = nt << 8;

  const char* XpC = (const char*)Xa + (size_t)m0 * (KA * 2);
  const char* WpC = (const char*)Wa + (size_t)n0 * (KA * 2);

  // Staging: idx = tid + j*512 -> row = idx>>2, slot4 = idx&3.
  // Source pre-swizzle slot4 ^= (row>>1)&3; LDS dest linear idx*16.
  int i0 = tid, i1 = tid + 512;
  int goff0 = (i0 >> 2) * (KA * 2) + (((i0 & 3) ^ ((i0 >> 3) & 3)) * 16);
  int goff1 = (i1 >> 2) * (KA * 2) + (((i1 & 3) ^ ((i1 >> 3) & 3)) * 16);
  int l0 = i0 * 16, l1 = i1 * 16;

  // Fragment read slot: (ln4 ^ ((row>>1)&3))*16; (row>>1)&3 == (lane>>1)&3.
  int rslot = ((ln4 ^ ((lane >> 1) & 3)) * 16);

  f32x4 acc[8][4] = {};
  half8 aF[8], bF[4];

  // prologue: stage ring slots 0,1,2 (tiles 0,1,2); drain tile 0; publish.
  STAGE4(0, 0); STAGE4(1, 1); STAGE4(2, 2);
  VMW8; BAR; SCHED0;

  // steady state: t = 0..127 (all stage t+3, guard vmcnt(8))
#pragma unroll 1
  for (int t4 = 0; t4 < NT - 4; t4 += 4) {
    TILE_FULL(0); TILE_FULL(1); TILE_FULL(2); TILE_FULL(3);
  }

  // peeled tail t = 128..131 (ring slots 0..3)
  { READS(0); STAGE4(131, 3); MFMA32; VMW8; BAR; SCHED0; }  // t=128
  { READS(1); MFMA32; VMW4; BAR; SCHED0; }                  // t=129
  { READS(2); MFMA32; VMW0; BAR; SCHED0; }                  // t=130
  { READS(3); MFMA32; }                                     // t=131

  // epilogue: + bias, fp32 store. C/D: col = lane&15, row = (lane>>4)*4 + reg
#pragma unroll
  for (int ni = 0; ni < 4; ++ni) {
    int n = n0 + wn + ni * 16 + ln15;
    float bz = bias[n];
#pragma unroll
    for (int mi = 0; mi < 8; ++mi) {
      f32x4 v = acc[mi][ni];
      int mb = m0 + wm + mi * 16 + ln4 * 4;
#pragma unroll
      for (int jj = 0; jj < 4; ++jj)
        out[(size_t)(mb + jj) * N_TOT + n] = v[jj] + bz;
    }
  }
}

// ---------------- fallback GEMM (reg-staged f32->f16, 128x128, low ws)
__global__ __launch_bounds__(256) void gemm_fallback(
    const float* __restrict__ x, const float* __restrict__ wgt,
    const float* __restrict__ midw, const float* __restrict__ lorabf,
    const float* __restrict__ bias, float* __restrict__ out) {
  __shared__ _Float16 As[128 * 64];
  __shared__ _Float16 Bs[128 * 64];
  int tid = threadIdx.x, lane = tid & 63, w = tid >> 6;
  int mt = blockIdx.x & 63, nt = blockIdx.x >> 6;
  int m0 = mt << 7, n0 = nt << 7;
  int wm = (w >> 1) * 64, wn = (w & 1) * 64;
  f32x4 acc[4][4] = {};
  for (int ks = 0; ks < 66; ++ks) {
    int k0 = ks * 64;
    const float *asrc, *bsrc; size_t astr, bstr; int ac, bc;
    if (ks < 64) { asrc = x;    astr = K_IN; ac = k0;        bsrc = wgt;    bstr = K_IN; bc = k0; }
    else         { asrc = midw; astr = 128;  ac = k0 - K_IN; bsrc = lorabf; bstr = 128;  bc = k0 - K_IN; }
#pragma unroll
    for (int it = 0; it < 8; ++it) {
      int idx = tid + it * 256;
      int r = idx >> 4, c4 = idx & 15;
      float4 fa = *(const float4*)(asrc + (size_t)(m0 + r) * astr + ac + c4 * 4);
      cvt_store4(As + r * 64 + c4 * 4, fa);
      float4 fb = *(const float4*)(bsrc + (size_t)(n0 + r) * bstr + bc + c4 * 4);
      cvt_store4(Bs + r * 64 + c4 * 4, fb);
    }
    __syncthreads();
#pragma unroll
    for (int kk = 0; kk < 2; ++kk) {
      half8 a[4], bf[4];
#pragma unroll
      for (int mi = 0; mi < 4; ++mi)
        a[mi] = *(const half8*)(As + (wm + mi * 16 + (lane & 15)) * 64 + kk * 32 + (lane >> 4) * 8);
#pragma unroll
      for (int ni = 0; ni < 4; ++ni)
        bf[ni] = *(const half8*)(Bs + (wn + ni * 16 + (lane & 15)) * 64 + kk * 32 + (lane >> 4) * 8);
#pragma unroll
      for (int mi = 0; mi < 4; ++mi)
#pragma unroll
        for (int ni = 0; ni < 4; ++ni)
          acc[mi][ni] = __builtin_amdgcn_mfma_f32_16x16x32_f16(a[mi], bf[ni], acc[mi][ni], 0, 0, 0);
    }
    __syncthreads();
  }
#pragma unroll
  for (int ni = 0; ni < 4; ++ni) {
    int n = n0 + wn + ni * 16 + (lane & 15);
    float bz = bias[n];
#pragma unroll
    for (int mi = 0; mi < 4; ++mi) {
      f32x4 v = acc[mi][ni];
      int mbase = m0 + wm + mi * 16 + (lane >> 4) * 4;
#pragma unroll
      for (int jj = 0; jj < 4; ++jj)
        out[(size_t)(mbase + jj) * N_TOT + n] = v[jj] + bz;
    }
  }
}

extern "C" void kernel_launch(void* const* d_in, const int* in_sizes, int n_in,
                              void* d_out, int out_size, void* d_ws, size_t ws_size,
                              hipStream_t stream) {
  const float* x      = (const float*)d_in[0];
  const float* router = (const float*)d_in[1];
  const float* wgt    = (const float*)d_in[2];
  const float* bias   = (const float*)d_in[3];
  const float* loraA  = (const float*)d_in[4];
  const float* loraB  = (const float*)d_in[5];
  float* out = (float*)d_out;
  char* ws = (char*)d_ws;

  const size_t XAUG_B = (size_t)M_TOT * KA * 2;    // 69,206,016
  const size_t WAUG_B = (size_t)N_TOT * KA * 2;    // 34,603,008
  const size_t LAH_B  = (size_t)128 * K_IN * 2;    //  1,048,576
  const size_t MIDW_B = (size_t)M_TOT * 128 * 4;   //  4,194,304
  bool fast = ws_size >= XAUG_B + WAUG_B + LAH_B;

  if (fast) {
    _Float16* Xa  = (_Float16*)ws;
    _Float16* Wa  = (_Float16*)(ws + XAUG_B);
    _Float16* lAh = (_Float16*)(ws + XAUG_B + WAUG_B);
    convert_f32_f16_t<12, KA><<<2048, 256, 0, stream>>>(x,   Xa, M_TOT * K_IN / 8);
    convert_f32_f16_t<12, KA><<<2048, 256, 0, stream>>>(wgt, Wa, N_TOT * K_IN / 8);
    convert_f32_f16_t<12, 4096><<<256, 256, 0, stream>>>(loraA, lAh, 128 * K_IN / 8);
    wtail_gather_f16<<<2048, 256, 0, stream>>>(loraB, Wa);
    mid3_kernel<<<512, 256, 0, stream>>>(Xa, lAh, router);
    gemm256<<<512, 512, 0, stream>>>(Xa, Wa, bias, out);
  } else {
    float* midw   = (float*)ws;
    float* lorabf = (float*)(ws + MIDW_B);
    lorabf_gather_f32<<<2048, 256, 0, stream>>>(loraB, lorabf);
    mid_kernel<<<256, 256, 0, stream>>>(x, loraA, router, midw);
    gemm_fallback<<<2048, 256, 0, stream>>>(x, wgt, midw, lorabf, bias, out);
  }
}

// Round 18
// 360.928 us; speedup vs baseline: 1.3087x; 1.1245x over previous
//
#include <hip/hip_runtime.h>

// SoftRoutedLoRALinear on MI355X — augmented-K f16 MFMA GEMM.
// out[m,n] = sum_k Xa[m,k]*Wa[n,k] + bias[n],  K = 4096 + 128 (LoRA tail)
//   Xa tail[m, e*16+r] = 2*router[b,e] * sum_i x[m,i]*lora_A[e,r,i]
//   Wa tail[n, e*16+r] = lora_B[e,n,r]
// Main GEMM: R15 ring-4 (best: 260us, MfmaUtil 53, serial LDS+MFMA floor).
// Prep: mid2r = mid2 with RING-3 counted-vmcnt pipeline (stage t+2, vmcnt(5)
// per tile) — hides the per-iteration HBM latency that made mid2 ~50us.

typedef _Float16 half8 __attribute__((ext_vector_type(8)));
typedef _Float16 half4 __attribute__((ext_vector_type(4)));
typedef float    f32x4 __attribute__((ext_vector_type(4)));

#define M_TOT 8192
#define N_TOT 4096
#define K_IN  4096
#define KA    4224
#define NT    132     // KA / 32

__device__ __forceinline__ void cvt_store4(_Float16* p, float4 f) {
  half4 h;
  h[0] = (_Float16)f.x; h[1] = (_Float16)f.y;
  h[2] = (_Float16)f.z; h[3] = (_Float16)f.w;
  *(half4*)p = h;
}

// ---------------- prep: f32 -> f16, compile-time source cols (no runtime div)
template <int LOG2C, int DCOLS>
__global__ __launch_bounds__(256) void convert_f32_f16_t(
    const float* __restrict__ src, _Float16* __restrict__ dst, int total8) {
  for (int i = blockIdx.x * 256 + threadIdx.x; i < total8;
       i += gridDim.x * 256) {
    int base = i << 3;
    int r = base >> LOG2C;
    int c = base & ((1 << LOG2C) - 1);
    const float4* s = (const float4*)(src + (size_t)base);
    float4 f0 = s[0], f1 = s[1];
    half8 h;
    h[0]=(_Float16)f0.x; h[1]=(_Float16)f0.y; h[2]=(_Float16)f0.z; h[3]=(_Float16)f0.w;
    h[4]=(_Float16)f1.x; h[5]=(_Float16)f1.y; h[6]=(_Float16)f1.z; h[7]=(_Float16)f1.w;
    *(half8*)(dst + (size_t)r * DCOLS + c) = h;
  }
}

// ---------------- prep: lora_B -> Wa tail (f16)
__global__ __launch_bounds__(256) void wtail_gather_f16(
    const float* __restrict__ loraB, _Float16* __restrict__ Wa) {
  int idx = blockIdx.x * 256 + threadIdx.x;       // 0 .. 4096*128-1
  int n = idx >> 7, j = idx & 127;
  int e = j >> 4, r = j & 15;
  Wa[(size_t)n * KA + K_IN + j] =
      (_Float16)loraB[((size_t)e * N_TOT + n) * 16 + r];
}

// ---------------- prep (fallback): lora_B -> fp32 [4096][128]
__global__ __launch_bounds__(256) void lorabf_gather_f32(
    const float* __restrict__ loraB, float* __restrict__ lorabf) {
  int idx = blockIdx.x * 256 + threadIdx.x;
  int n = idx >> 7, j = idx & 127;
  int e = j >> 4, r = j & 15;
  lorabf[(size_t)n * 128 + j] = loraB[((size_t)e * N_TOT + n) * 16 + r];
}

// ---------------- mid2r: ring-3 pipelined x(f16)@loraA(f16)^T -> Xa tail
// 256 blocks; slot = 20KB (A 4KB + B 16KB); stage t+2, vmcnt(5)/tile.
#define MVMW5 asm volatile("s_waitcnt vmcnt(5)" ::: "memory")
#define MVMW0 asm volatile("s_waitcnt vmcnt(0)" ::: "memory")
#define MGLOAD(src, dst) __builtin_amdgcn_global_load_lds( \
    (const __attribute__((address_space(1))) void*)(src), \
    (__attribute__((address_space(3))) void*)(dst), 16, 0, 0)

__global__ __launch_bounds__(256) void mid2r_kernel(
    _Float16* __restrict__ Xa, const _Float16* __restrict__ lAh,
    const float* __restrict__ router) {
  __shared__ __align__(16) char MLDS[61440];   // 3 x (4KB A + 16KB B)
  int tid = threadIdx.x, lane = tid & 63, w = tid >> 6;
  int m0 = blockIdx.x * 32;
  int b = m0 >> 11;
  f32x4 acc[2][2] = {};

  int scol = ((lane & 7) ^ (lane >> 3)) * 16;   // pre-swizzled source slot
  int ln15 = lane & 15, ln4 = lane >> 4;

  // per-thread staging offsets (loop-invariant except ks*128 byte advance)
  int gA = (w * 8 + (lane >> 3)) * (KA * 2) + scol;         // + m0 row base
  int lA = w * 1024 + lane * 16;
  int gB[4], lB[4];
#pragma unroll
  for (int i = 0; i < 4; ++i) {
    gB[i] = ((w * 4 + i) * 8 + (lane >> 3)) * (4096 * 2) + scol;
    lB[i] = (w * 4 + i) * 1024 + lane * 16;
  }
  const char* xaB = (const char*)Xa + (size_t)m0 * (KA * 2);
  const char* lAB = (const char*)lAh;

#define MSTAGE(KS, SL) do { \
  char* base_ = MLDS + (SL) * 20480; \
  MGLOAD(xaB + gA + (KS) * 128, base_ + lA); \
  _Pragma("unroll") for (int i = 0; i < 4; ++i) \
    MGLOAD(lAB + gB[i] + (KS) * 128, base_ + 4096 + lB[i]); \
  } while (0)

#define MCOMP(SL) do { \
  const char* As_ = MLDS + (SL) * 20480; \
  const char* Bs_ = As_ + 4096; \
  _Pragma("unroll") for (int kk = 0; kk < 2; ++kk) { \
    int rs = (((kk * 4 + ln4) ^ (ln15 & 7)) << 4); \
    half8 a[2], bf[2]; \
    _Pragma("unroll") for (int mi = 0; mi < 2; ++mi) \
      a[mi] = *(const half8*)(As_ + (mi * 16 + ln15) * 128 + rs); \
    _Pragma("unroll") for (int ni = 0; ni < 2; ++ni) \
      bf[ni] = *(const half8*)(Bs_ + (w * 32 + ni * 16 + ln15) * 128 + rs); \
    _Pragma("unroll") for (int mi = 0; mi < 2; ++mi) \
      _Pragma("unroll") for (int ni = 0; ni < 2; ++ni) \
        acc[mi][ni] = __builtin_amdgcn_mfma_f32_16x16x32_f16( \
            a[mi], bf[ni], acc[mi][ni], 0, 0, 0); \
  } } while (0)

  // prologue: tiles 0,1 into slots 0,1; drain tile 0 (vmcnt(5)); publish.
  MSTAGE(0, 0); MSTAGE(1, 1);
  MVMW5; __syncthreads();

  // steady: t = 0..59 (stage t+2, guard vmcnt(5))
#pragma unroll 1
  for (int t3 = 0; t3 < 60; t3 += 3) {
    { MCOMP(0); MSTAGE(t3 + 2, 2); MVMW5; __syncthreads(); }
    { MCOMP(1); MSTAGE(t3 + 3, 0); MVMW5; __syncthreads(); }
    { MCOMP(2); MSTAGE(t3 + 4, 1); MVMW5; __syncthreads(); }
  }
  // tail: t=60 (stage 62), 61 (stage 63), 62, 63
  { MCOMP(0); MSTAGE(62, 2); MVMW5; __syncthreads(); }
  { MCOMP(1); MSTAGE(63, 0); MVMW5; __syncthreads(); }
  { MCOMP(2); MVMW0; __syncthreads(); }
  { MCOMP(0); }

#pragma unroll
  for (int ni = 0; ni < 2; ++ni) {
    int j = w * 32 + ni * 16 + ln15;
    int e = j >> 4;
    float sc = 2.0f * router[b * 8 + e];
#pragma unroll
    for (int mi = 0; mi < 2; ++mi) {
      f32x4 v = acc[mi][ni];
#pragma unroll
      for (int jj = 0; jj < 4; ++jj) {
        int m = m0 + mi * 16 + ln4 * 4 + jj;
        Xa[(size_t)m * KA + K_IN + j] = (_Float16)(v[jj] * sc);
      }
    }
  }
#undef MSTAGE
#undef MCOMP
}

// ---------------- fallback mid (f32 sources -> f32 midw, router fused)
__global__ __launch_bounds__(256) void mid_kernel(
    const float* __restrict__ x, const float* __restrict__ loraA,
    const float* __restrict__ router, float* __restrict__ midw) {
  __shared__ _Float16 As[32 * 64];
  __shared__ _Float16 Bs[128 * 64];
  int tid = threadIdx.x, lane = tid & 63, w = tid >> 6;
  int m0 = blockIdx.x * 32;
  int b = m0 >> 11;
  f32x4 acc[2][2] = {};
  for (int ks = 0; ks < 64; ++ks) {
    int k0 = ks * 64;
#pragma unroll
    for (int it = 0; it < 2; ++it) {
      int idx = tid + it * 256;
      int r = idx >> 4, c4 = idx & 15;
      float4 f = *(const float4*)(x + (size_t)(m0 + r) * K_IN + k0 + c4 * 4);
      cvt_store4(As + r * 64 + c4 * 4, f);
    }
#pragma unroll
    for (int it = 0; it < 8; ++it) {
      int idx = tid + it * 256;
      int r = idx >> 4, c4 = idx & 15;
      float4 f = *(const float4*)(loraA + (size_t)r * K_IN + k0 + c4 * 4);
      cvt_store4(Bs + r * 64 + c4 * 4, f);
    }
    __syncthreads();
#pragma unroll
    for (int kk = 0; kk < 2; ++kk) {
      half8 a[2], bf[2];
#pragma unroll
      for (int mi = 0; mi < 2; ++mi)
        a[mi] = *(const half8*)(As + (mi * 16 + (lane & 15)) * 64 + kk * 32 + (lane >> 4) * 8);
#pragma unroll
      for (int ni = 0; ni < 2; ++ni)
        bf[ni] = *(const half8*)(Bs + (w * 32 + ni * 16 + (lane & 15)) * 64 + kk * 32 + (lane >> 4) * 8);
#pragma unroll
      for (int mi = 0; mi < 2; ++mi)
#pragma unroll
        for (int ni = 0; ni < 2; ++ni)
          acc[mi][ni] = __builtin_amdgcn_mfma_f32_16x16x32_f16(a[mi], bf[ni], acc[mi][ni], 0, 0, 0);
    }
    __syncthreads();
  }
#pragma unroll
  for (int ni = 0; ni < 2; ++ni) {
    int j = w * 32 + ni * 16 + (lane & 15);
    int e = j >> 4;
    float sc = 2.0f * router[b * 8 + e];
#pragma unroll
    for (int mi = 0; mi < 2; ++mi) {
      f32x4 v = acc[mi][ni];
#pragma unroll
      for (int jj = 0; jj < 4; ++jj) {
        int m = m0 + mi * 16 + (lane >> 4) * 4 + jj;
        midw[(size_t)m * 128 + j] = v[jj] * sc;
      }
    }
  }
}

// ====== main GEMM: 256x256, BK=32, 8 waves, ring-4, compiler-counted lgkm ===
#define BAR    __builtin_amdgcn_s_barrier()
#define SCHED0 __builtin_amdgcn_sched_barrier(0)
#define VMW8   asm volatile("s_waitcnt vmcnt(8)" ::: "memory")
#define VMW4   asm volatile("s_waitcnt vmcnt(4)" ::: "memory")
#define VMW0   asm volatile("s_waitcnt vmcnt(0)" ::: "memory")
#define GLOAD(src, dst) __builtin_amdgcn_global_load_lds( \
    (const __attribute__((address_space(1))) void*)(src), \
    (__attribute__((address_space(3))) void*)(dst), 16, 0, 0)

// A slot SL at LDS bytes [SL*16384, +16K); B at 65536 + SL*16384.
// B read FIRST so the first MFMA (aF[0] x bF[0..3]) depends on reads 1-5;
// the compiler's counted lgkmcnt lets reads 6-12 drain under the MFMA burst.
#define READS(SL) do { \
  _Pragma("unroll") for (int ni = 0; ni < 4; ++ni) \
    bF[ni] = *(const half8*)(LDS + 65536 + (SL) * 16384 + \
                             (wn + ni * 16 + ln15) * 64 + rslot); \
  _Pragma("unroll") for (int mi = 0; mi < 8; ++mi) \
    aF[mi] = *(const half8*)(LDS + (SL) * 16384 + \
                             (wm + mi * 16 + ln15) * 64 + rslot); \
  } while (0)

// stage K32-tile TT into ring slot SL (A:2 + B:2 gloads, linear LDS dest)
#define STAGE4(TT, SL) do { \
  const char* sA_ = XpC + (size_t)(TT) * 64; \
  const char* sB_ = WpC + (size_t)(TT) * 64; \
  GLOAD(sA_ + goff0, LDS + (SL) * 16384 + l0); \
  GLOAD(sA_ + goff1, LDS + (SL) * 16384 + l1); \
  GLOAD(sB_ + goff0, LDS + 65536 + (SL) * 16384 + l0); \
  GLOAD(sB_ + goff1, LDS + 65536 + (SL) * 16384 + l1); \
  } while (0)

#define MFMA32 do { \
  _Pragma("unroll") for (int mi = 0; mi < 8; ++mi) \
    _Pragma("unroll") for (int ni = 0; ni < 4; ++ni) \
      acc[mi][ni] = __builtin_amdgcn_mfma_f32_16x16x32_f16( \
          aF[mi], bF[ni], acc[mi][ni], 0, 0, 0); \
  } while (0)

// steady tile: NO explicit lgkm drain — compiler-counted waits interleave
// read-drain with the MFMA burst. vmcnt(8) ring guard unchanged.
#define TILE_FULL(SL) do { \
  READS(SL); \
  STAGE4(t4 + (SL) + 3, ((SL) + 3) & 3); \
  MFMA32; VMW8; BAR; SCHED0; \
  } while (0)

__global__ __launch_bounds__(512, 2) void gemm256(
    const _Float16* __restrict__ Xa, const _Float16* __restrict__ Wa,
    const float* __restrict__ bias, float* __restrict__ out) {
  __shared__ __align__(16) char LDS[131072];   // A ring 64K | B ring 64K

  int tid = threadIdx.x, lane = tid & 63, w = tid >> 6;
  int ln15 = lane & 15, ln4 = lane >> 4;
  int wm = (w >> 2) * 128, wn = (w & 3) * 64;

  // T1: XCD chunk swizzle — 512 blocks = 8 XCDs x 64; each XCD an 8x8 chunk.
  int bid = blockIdx.x;
  int xcd = bid & 7, idx = bid >> 3;
  int mt = (xcd & 3) * 8 + (idx & 7);
  int nt = (xcd >> 2) * 8 + (idx >> 3);
  int m0 = mt << 8, n0 = nt << 8;

  const char* XpC = (const char*)Xa + (size_t)m0 * (KA * 2);
  const char* WpC = (const char*)Wa + (size_t)n0 * (KA * 2);

  // Staging: idx = tid + j*512 -> row = idx>>2, slot4 = idx&3.
  // Source pre-swizzle slot4 ^= (row>>1)&3; LDS dest linear idx*16.
  int i0 = tid, i1 = tid + 512;
  int goff0 = (i0 >> 2) * (KA * 2) + (((i0 & 3) ^ ((i0 >> 3) & 3)) * 16);
  int goff1 = (i1 >> 2) * (KA * 2) + (((i1 & 3) ^ ((i1 >> 3) & 3)) * 16);
  int l0 = i0 * 16, l1 = i1 * 16;

  // Fragment read slot: (ln4 ^ ((row>>1)&3))*16; (row>>1)&3 == (lane>>1)&3.
  int rslot = ((ln4 ^ ((lane >> 1) & 3)) * 16);

  f32x4 acc[8][4] = {};
  half8 aF[8], bF[4];

  // prologue: stage ring slots 0,1,2 (tiles 0,1,2); drain tile 0; publish.
  STAGE4(0, 0); STAGE4(1, 1); STAGE4(2, 2);
  VMW8; BAR; SCHED0;

  // steady state: t = 0..127 (all stage t+3, guard vmcnt(8))
#pragma unroll 1
  for (int t4 = 0; t4 < NT - 4; t4 += 4) {
    TILE_FULL(0); TILE_FULL(1); TILE_FULL(2); TILE_FULL(3);
  }

  // peeled tail t = 128..131 (ring slots 0..3)
  { READS(0); STAGE4(131, 3); MFMA32; VMW8; BAR; SCHED0; }  // t=128
  { READS(1); MFMA32; VMW4; BAR; SCHED0; }                  // t=129
  { READS(2); MFMA32; VMW0; BAR; SCHED0; }                  // t=130
  { READS(3); MFMA32; }                                     // t=131

  // epilogue: + bias, fp32 store. C/D: col = lane&15, row = (lane>>4)*4 + reg
#pragma unroll
  for (int ni = 0; ni < 4; ++ni) {
    int n = n0 + wn + ni * 16 + ln15;
    float bz = bias[n];
#pragma unroll
    for (int mi = 0; mi < 8; ++mi) {
      f32x4 v = acc[mi][ni];
      int mb = m0 + wm + mi * 16 + ln4 * 4;
#pragma unroll
      for (int jj = 0; jj < 4; ++jj)
        out[(size_t)(mb + jj) * N_TOT + n] = v[jj] + bz;
    }
  }
}

// ---------------- fallback GEMM (reg-staged f32->f16, 128x128, low ws)
__global__ __launch_bounds__(256) void gemm_fallback(
    const float* __restrict__ x, const float* __restrict__ wgt,
    const float* __restrict__ midw, const float* __restrict__ lorabf,
    const float* __restrict__ bias, float* __restrict__ out) {
  __shared__ _Float16 As[128 * 64];
  __shared__ _Float16 Bs[128 * 64];
  int tid = threadIdx.x, lane = tid & 63, w = tid >> 6;
  int mt = blockIdx.x & 63, nt = blockIdx.x >> 6;
  int m0 = mt << 7, n0 = nt << 7;
  int wm = (w >> 1) * 64, wn = (w & 1) * 64;
  f32x4 acc[4][4] = {};
  for (int ks = 0; ks < 66; ++ks) {
    int k0 = ks * 64;
    const float *asrc, *bsrc; size_t astr, bstr; int ac, bc;
    if (ks < 64) { asrc = x;    astr = K_IN; ac = k0;        bsrc = wgt;    bstr = K_IN; bc = k0; }
    else         { asrc = midw; astr = 128;  ac = k0 - K_IN; bsrc = lorabf; bstr = 128;  bc = k0 - K_IN; }
#pragma unroll
    for (int it = 0; it < 8; ++it) {
      int idx = tid + it * 256;
      int r = idx >> 4, c4 = idx & 15;
      float4 fa = *(const float4*)(asrc + (size_t)(m0 + r) * astr + ac + c4 * 4);
      cvt_store4(As + r * 64 + c4 * 4, fa);
      float4 fb = *(const float4*)(bsrc + (size_t)(n0 + r) * bstr + bc + c4 * 4);
      cvt_store4(Bs + r * 64 + c4 * 4, fb);
    }
    __syncthreads();
#pragma unroll
    for (int kk = 0; kk < 2; ++kk) {
      half8 a[4], bf[4];
#pragma unroll
      for (int mi = 0; mi < 4; ++mi)
        a[mi] = *(const half8*)(As + (wm + mi * 16 + (lane & 15)) * 64 + kk * 32 + (lane >> 4) * 8);
#pragma unroll
      for (int ni = 0; ni < 4; ++ni)
        bf[ni] = *(const half8*)(Bs + (wn + ni * 16 + (lane & 15)) * 64 + kk * 32 + (lane >> 4) * 8);
#pragma unroll
      for (int mi = 0; mi < 4; ++mi)
#pragma unroll
        for (int ni = 0; ni < 4; ++ni)
          acc[mi][ni] = __builtin_amdgcn_mfma_f32_16x16x32_f16(a[mi], bf[ni], acc[mi][ni], 0, 0, 0);
    }
    __syncthreads();
  }
#pragma unroll
  for (int ni = 0; ni < 4; ++ni) {
    int n = n0 + wn + ni * 16 + (lane & 15);
    float bz = bias[n];
#pragma unroll
    for (int mi = 0; mi < 4; ++mi) {
      f32x4 v = acc[mi][ni];
      int mbase = m0 + wm + mi * 16 + (lane >> 4) * 4;
#pragma unroll
      for (int jj = 0; jj < 4; ++jj)
        out[(size_t)(mbase + jj) * N_TOT + n] = v[jj] + bz;
    }
  }
}

extern "C" void kernel_launch(void* const* d_in, const int* in_sizes, int n_in,
                              void* d_out, int out_size, void* d_ws, size_t ws_size,
                              hipStream_t stream) {
  const float* x      = (const float*)d_in[0];
  const float* router = (const float*)d_in[1];
  const float* wgt    = (const float*)d_in[2];
  const float* bias   = (const float*)d_in[3];
  const float* loraA  = (const float*)d_in[4];
  const float* loraB  = (const float*)d_in[5];
  float* out = (float*)d_out;
  char* ws = (char*)d_ws;

  const size_t XAUG_B = (size_t)M_TOT * KA * 2;    // 69,206,016
  const size_t WAUG_B = (size_t)N_TOT * KA * 2;    // 34,603,008
  const size_t LAH_B  = (size_t)128 * K_IN * 2;    //  1,048,576
  const size_t MIDW_B = (size_t)M_TOT * 128 * 4;   //  4,194,304
  bool fast = ws_size >= XAUG_B + WAUG_B + LAH_B;

  if (fast) {
    _Float16* Xa  = (_Float16*)ws;
    _Float16* Wa  = (_Float16*)(ws + XAUG_B);
    _Float16* lAh = (_Float16*)(ws + XAUG_B + WAUG_B);
    convert_f32_f16_t<12, KA><<<2048, 256, 0, stream>>>(x,   Xa, M_TOT * K_IN / 8);
    convert_f32_f16_t<12, KA><<<2048, 256, 0, stream>>>(wgt, Wa, N_TOT * K_IN / 8);
    convert_f32_f16_t<12, 4096><<<256, 256, 0, stream>>>(loraA, lAh, 128 * K_IN / 8);
    wtail_gather_f16<<<2048, 256, 0, stream>>>(loraB, Wa);
    mid2r_kernel<<<256, 256, 0, stream>>>(Xa, lAh, router);
    gemm256<<<512, 512, 0, stream>>>(Xa, Wa, bias, out);
  } else {
    float* midw   = (float*)ws;
    float* lorabf = (float*)(ws + MIDW_B);
    lorabf_gather_f32<<<2048, 256, 0, stream>>>(loraB, lorabf);
    mid_kernel<<<256, 256, 0, stream>>>(x, loraA, router, midw);
    gemm_fallback<<<2048, 256, 0, stream>>>(x, wgt, midw, lorabf, bias, out);
  }
}

// Round 19
// 360.012 us; speedup vs baseline: 1.3120x; 1.0025x over previous
//
#include <hip/hip_runtime.h>

// SoftRoutedLoRALinear on MI355X — augmented-K f16 MFMA GEMM.
// out[m,n] = sum_k Xa[m,k]*Wa[n,k] + bias[n],  K = 4096 + 128 (LoRA tail)
//   Xa tail[m, e*16+r] = 2*router[b,e] * sum_i x[m,i]*lora_A[e,r,i]
//   Wa tail[n, e*16+r] = lora_B[e,n,r]
// Main GEMM: R15 ring-4 (260us, MfmaUtil 53 — serial LDS+MFMA floor).
// Prep: ONE fused prep_all kernel (x/wgt/lA converts + wtail gather via
// block-range partition) — removes 3 launch gaps; then ring-3 mid2r.

typedef _Float16 half8 __attribute__((ext_vector_type(8)));
typedef _Float16 half4 __attribute__((ext_vector_type(4)));
typedef float    f32x4 __attribute__((ext_vector_type(4)));

#define M_TOT 8192
#define N_TOT 4096
#define K_IN  4096
#define KA    4224
#define NT    132     // KA / 32

__device__ __forceinline__ void cvt_store4(_Float16* p, float4 f) {
  half4 h;
  h[0] = (_Float16)f.x; h[1] = (_Float16)f.y;
  h[2] = (_Float16)f.z; h[3] = (_Float16)f.w;
  *(half4*)p = h;
}

__device__ __forceinline__ void cvt8(const float* src, _Float16* dst) {
  const float4* s = (const float4*)src;
  float4 f0 = s[0], f1 = s[1];
  half8 h;
  h[0]=(_Float16)f0.x; h[1]=(_Float16)f0.y; h[2]=(_Float16)f0.z; h[3]=(_Float16)f0.w;
  h[4]=(_Float16)f1.x; h[5]=(_Float16)f1.y; h[6]=(_Float16)f1.z; h[7]=(_Float16)f1.w;
  *(half8*)dst = h;
}

// ---------------- fused prep: block-range partition
//   [0,2048):    x   (f32[8192][4096]) -> Xa (f16[8192][4224])
//   [2048,3072): wgt (f32[4096][4096]) -> Wa (f16[4096][4224])
//   [3072,3104): loraA (f32[128][4096]) -> lAh (f16[128][4096])
//   [3104,3360): loraB gather -> Wa tail
__global__ __launch_bounds__(256) void prep_all(
    const float* __restrict__ x, const float* __restrict__ wgt,
    const float* __restrict__ loraA, const float* __restrict__ loraB,
    _Float16* __restrict__ Xa, _Float16* __restrict__ Wa,
    _Float16* __restrict__ lAh) {
  int bid = blockIdx.x, tid = threadIdx.x;
  if (bid < 2048) {
    for (int i = bid * 256 + tid; i < M_TOT * K_IN / 8; i += 2048 * 256) {
      int base = i << 3;
      int r = base >> 12, c = base & 4095;
      cvt8(x + (size_t)base, Xa + (size_t)r * KA + c);
    }
  } else if (bid < 3072) {
    for (int i = (bid - 2048) * 256 + tid; i < N_TOT * K_IN / 8; i += 1024 * 256) {
      int base = i << 3;
      int r = base >> 12, c = base & 4095;
      cvt8(wgt + (size_t)base, Wa + (size_t)r * KA + c);
    }
  } else if (bid < 3104) {
    for (int i = (bid - 3072) * 256 + tid; i < 128 * K_IN / 8; i += 32 * 256) {
      int base = i << 3;
      cvt8(loraA + (size_t)base, lAh + (size_t)base);
    }
  } else {
    for (int i = (bid - 3104) * 256 + tid; i < N_TOT * 128; i += 256 * 256) {
      int n = i >> 7, j = i & 127;
      int e = j >> 4, r = j & 15;
      Wa[(size_t)n * KA + K_IN + j] =
          (_Float16)loraB[((size_t)e * N_TOT + n) * 16 + r];
    }
  }
}

// ---------------- prep (fallback): lora_B -> fp32 [4096][128]
__global__ __launch_bounds__(256) void lorabf_gather_f32(
    const float* __restrict__ loraB, float* __restrict__ lorabf) {
  int idx = blockIdx.x * 256 + threadIdx.x;
  int n = idx >> 7, j = idx & 127;
  int e = j >> 4, r = j & 15;
  lorabf[(size_t)n * 128 + j] = loraB[((size_t)e * N_TOT + n) * 16 + r];
}

// ---------------- mid2r: ring-3 pipelined x(f16)@loraA(f16)^T -> Xa tail
#define MVMW5 asm volatile("s_waitcnt vmcnt(5)" ::: "memory")
#define MVMW0 asm volatile("s_waitcnt vmcnt(0)" ::: "memory")
#define MGLOAD(src, dst) __builtin_amdgcn_global_load_lds( \
    (const __attribute__((address_space(1))) void*)(src), \
    (__attribute__((address_space(3))) void*)(dst), 16, 0, 0)

__global__ __launch_bounds__(256) void mid2r_kernel(
    _Float16* __restrict__ Xa, const _Float16* __restrict__ lAh,
    const float* __restrict__ router) {
  __shared__ __align__(16) char MLDS[61440];   // 3 x (4KB A + 16KB B)
  int tid = threadIdx.x, lane = tid & 63, w = tid >> 6;
  int m0 = blockIdx.x * 32;
  int b = m0 >> 11;
  f32x4 acc[2][2] = {};

  int scol = ((lane & 7) ^ (lane >> 3)) * 16;   // pre-swizzled source slot
  int ln15 = lane & 15, ln4 = lane >> 4;

  int gA = (w * 8 + (lane >> 3)) * (KA * 2) + scol;
  int lA = w * 1024 + lane * 16;
  int gB[4], lB[4];
#pragma unroll
  for (int i = 0; i < 4; ++i) {
    gB[i] = ((w * 4 + i) * 8 + (lane >> 3)) * (4096 * 2) + scol;
    lB[i] = (w * 4 + i) * 1024 + lane * 16;
  }
  const char* xaB = (const char*)Xa + (size_t)m0 * (KA * 2);
  const char* lAB = (const char*)lAh;

#define MSTAGE(KS, SL) do { \
  char* base_ = MLDS + (SL) * 20480; \
  MGLOAD(xaB + gA + (KS) * 128, base_ + lA); \
  _Pragma("unroll") for (int i = 0; i < 4; ++i) \
    MGLOAD(lAB + gB[i] + (KS) * 128, base_ + 4096 + lB[i]); \
  } while (0)

#define MCOMP(SL) do { \
  const char* As_ = MLDS + (SL) * 20480; \
  const char* Bs_ = As_ + 4096; \
  _Pragma("unroll") for (int kk = 0; kk < 2; ++kk) { \
    int rs = (((kk * 4 + ln4) ^ (ln15 & 7)) << 4); \
    half8 a[2], bf[2]; \
    _Pragma("unroll") for (int mi = 0; mi < 2; ++mi) \
      a[mi] = *(const half8*)(As_ + (mi * 16 + ln15) * 128 + rs); \
    _Pragma("unroll") for (int ni = 0; ni < 2; ++ni) \
      bf[ni] = *(const half8*)(Bs_ + (w * 32 + ni * 16 + ln15) * 128 + rs); \
    _Pragma("unroll") for (int mi = 0; mi < 2; ++mi) \
      _Pragma("unroll") for (int ni = 0; ni < 2; ++ni) \
        acc[mi][ni] = __builtin_amdgcn_mfma_f32_16x16x32_f16( \
            a[mi], bf[ni], acc[mi][ni], 0, 0, 0); \
  } } while (0)

  MSTAGE(0, 0); MSTAGE(1, 1);
  MVMW5; __syncthreads();

#pragma unroll 1
  for (int t3 = 0; t3 < 60; t3 += 3) {
    { MCOMP(0); MSTAGE(t3 + 2, 2); MVMW5; __syncthreads(); }
    { MCOMP(1); MSTAGE(t3 + 3, 0); MVMW5; __syncthreads(); }
    { MCOMP(2); MSTAGE(t3 + 4, 1); MVMW5; __syncthreads(); }
  }
  { MCOMP(0); MSTAGE(62, 2); MVMW5; __syncthreads(); }
  { MCOMP(1); MSTAGE(63, 0); MVMW5; __syncthreads(); }
  { MCOMP(2); MVMW0; __syncthreads(); }
  { MCOMP(0); }

#pragma unroll
  for (int ni = 0; ni < 2; ++ni) {
    int j = w * 32 + ni * 16 + ln15;
    int e = j >> 4;
    float sc = 2.0f * router[b * 8 + e];
#pragma unroll
    for (int mi = 0; mi < 2; ++mi) {
      f32x4 v = acc[mi][ni];
#pragma unroll
      for (int jj = 0; jj < 4; ++jj) {
        int m = m0 + mi * 16 + ln4 * 4 + jj;
        Xa[(size_t)m * KA + K_IN + j] = (_Float16)(v[jj] * sc);
      }
    }
  }
#undef MSTAGE
#undef MCOMP
}

// ---------------- fallback mid (f32 sources -> f32 midw, router fused)
__global__ __launch_bounds__(256) void mid_kernel(
    const float* __restrict__ x, const float* __restrict__ loraA,
    const float* __restrict__ router, float* __restrict__ midw) {
  __shared__ _Float16 As[32 * 64];
  __shared__ _Float16 Bs[128 * 64];
  int tid = threadIdx.x, lane = tid & 63, w = tid >> 6;
  int m0 = blockIdx.x * 32;
  int b = m0 >> 11;
  f32x4 acc[2][2] = {};
  for (int ks = 0; ks < 64; ++ks) {
    int k0 = ks * 64;
#pragma unroll
    for (int it = 0; it < 2; ++it) {
      int idx = tid + it * 256;
      int r = idx >> 4, c4 = idx & 15;
      float4 f = *(const float4*)(x + (size_t)(m0 + r) * K_IN + k0 + c4 * 4);
      cvt_store4(As + r * 64 + c4 * 4, f);
    }
#pragma unroll
    for (int it = 0; it < 8; ++it) {
      int idx = tid + it * 256;
      int r = idx >> 4, c4 = idx & 15;
      float4 f = *(const float4*)(loraA + (size_t)r * K_IN + k0 + c4 * 4);
      cvt_store4(Bs + r * 64 + c4 * 4, f);
    }
    __syncthreads();
#pragma unroll
    for (int kk = 0; kk < 2; ++kk) {
      half8 a[2], bf[2];
#pragma unroll
      for (int mi = 0; mi < 2; ++mi)
        a[mi] = *(const half8*)(As + (mi * 16 + (lane & 15)) * 64 + kk * 32 + (lane >> 4) * 8);
#pragma unroll
      for (int ni = 0; ni < 2; ++ni)
        bf[ni] = *(const half8*)(Bs + (w * 32 + ni * 16 + (lane & 15)) * 64 + kk * 32 + (lane >> 4) * 8);
#pragma unroll
      for (int mi = 0; mi < 2; ++mi)
#pragma unroll
        for (int ni = 0; ni < 2; ++ni)
          acc[mi][ni] = __builtin_amdgcn_mfma_f32_16x16x32_f16(a[mi], bf[ni], acc[mi][ni], 0, 0, 0);
    }
    __syncthreads();
  }
#pragma unroll
  for (int ni = 0; ni < 2; ++ni) {
    int j = w * 32 + ni * 16 + (lane & 15);
    int e = j >> 4;
    float sc = 2.0f * router[b * 8 + e];
#pragma unroll
    for (int mi = 0; mi < 2; ++mi) {
      f32x4 v = acc[mi][ni];
#pragma unroll
      for (int jj = 0; jj < 4; ++jj) {
        int m = m0 + mi * 16 + (lane >> 4) * 4 + jj;
        midw[(size_t)m * 128 + j] = v[jj] * sc;
      }
    }
  }
}

// ====== main GEMM: 256x256, BK=32, 8 waves, ring-4, compiler-counted lgkm ===
#define BAR    __builtin_amdgcn_s_barrier()
#define SCHED0 __builtin_amdgcn_sched_barrier(0)
#define VMW8   asm volatile("s_waitcnt vmcnt(8)" ::: "memory")
#define VMW4   asm volatile("s_waitcnt vmcnt(4)" ::: "memory")
#define VMW0   asm volatile("s_waitcnt vmcnt(0)" ::: "memory")
#define GLOAD(src, dst) __builtin_amdgcn_global_load_lds( \
    (const __attribute__((address_space(1))) void*)(src), \
    (__attribute__((address_space(3))) void*)(dst), 16, 0, 0)

// A slot SL at LDS bytes [SL*16384, +16K); B at 65536 + SL*16384.
// B read FIRST so the first MFMA (aF[0] x bF[0..3]) depends on reads 1-5;
// the compiler's counted lgkmcnt lets reads 6-12 drain under the MFMA burst.
#define READS(SL) do { \
  _Pragma("unroll") for (int ni = 0; ni < 4; ++ni) \
    bF[ni] = *(const half8*)(LDS + 65536 + (SL) * 16384 + \
                             (wn + ni * 16 + ln15) * 64 + rslot); \
  _Pragma("unroll") for (int mi = 0; mi < 8; ++mi) \
    aF[mi] = *(const half8*)(LDS + (SL) * 16384 + \
                             (wm + mi * 16 + ln15) * 64 + rslot); \
  } while (0)

// stage K32-tile TT into ring slot SL (A:2 + B:2 gloads, linear LDS dest)
#define STAGE4(TT, SL) do { \
  const char* sA_ = XpC + (size_t)(TT) * 64; \
  const char* sB_ = WpC + (size_t)(TT) * 64; \
  GLOAD(sA_ + goff0, LDS + (SL) * 16384 + l0); \
  GLOAD(sA_ + goff1, LDS + (SL) * 16384 + l1); \
  GLOAD(sB_ + goff0, LDS + 65536 + (SL) * 16384 + l0); \
  GLOAD(sB_ + goff1, LDS + 65536 + (SL) * 16384 + l1); \
  } while (0)

#define MFMA32 do { \
  _Pragma("unroll") for (int mi = 0; mi < 8; ++mi) \
    _Pragma("unroll") for (int ni = 0; ni < 4; ++ni) \
      acc[mi][ni] = __builtin_amdgcn_mfma_f32_16x16x32_f16( \
          aF[mi], bF[ni], acc[mi][ni], 0, 0, 0); \
  } while (0)

#define TILE_FULL(SL) do { \
  READS(SL); \
  STAGE4(t4 + (SL) + 3, ((SL) + 3) & 3); \
  MFMA32; VMW8; BAR; SCHED0; \
  } while (0)

__global__ __launch_bounds__(512, 2) void gemm256(
    const _Float16* __restrict__ Xa, const _Float16* __restrict__ Wa,
    const float* __restrict__ bias, float* __restrict__ out) {
  __shared__ __align__(16) char LDS[131072];   // A ring 64K | B ring 64K

  int tid = threadIdx.x, lane = tid & 63, w = tid >> 6;
  int ln15 = lane & 15, ln4 = lane >> 4;
  int wm = (w >> 2) * 128, wn = (w & 3) * 64;

  // T1: XCD chunk swizzle — 512 blocks = 8 XCDs x 64; each XCD an 8x8 chunk.
  int bid = blockIdx.x;
  int xcd = bid & 7, idx = bid >> 3;
  int mt = (xcd & 3) * 8 + (idx & 7);
  int nt = (xcd >> 2) * 8 + (idx >> 3);
  int m0 = mt << 8, n0 = nt << 8;

  const char* XpC = (const char*)Xa + (size_t)m0 * (KA * 2);
  const char* WpC = (const char*)Wa + (size_t)n0 * (KA * 2);

  // Staging: idx = tid + j*512 -> row = idx>>2, slot4 = idx&3.
  // Source pre-swizzle slot4 ^= (row>>1)&3; LDS dest linear idx*16.
  int i0 = tid, i1 = tid + 512;
  int goff0 = (i0 >> 2) * (KA * 2) + (((i0 & 3) ^ ((i0 >> 3) & 3)) * 16);
  int goff1 = (i1 >> 2) * (KA * 2) + (((i1 & 3) ^ ((i1 >> 3) & 3)) * 16);
  int l0 = i0 * 16, l1 = i1 * 16;

  // Fragment read slot: (ln4 ^ ((row>>1)&3))*16; (row>>1)&3 == (lane>>1)&3.
  int rslot = ((ln4 ^ ((lane >> 1) & 3)) * 16);

  f32x4 acc[8][4] = {};
  half8 aF[8], bF[4];

  // prologue: stage ring slots 0,1,2 (tiles 0,1,2); drain tile 0; publish.
  STAGE4(0, 0); STAGE4(1, 1); STAGE4(2, 2);
  VMW8; BAR; SCHED0;

  // steady state: t = 0..127 (all stage t+3, guard vmcnt(8))
#pragma unroll 1
  for (int t4 = 0; t4 < NT - 4; t4 += 4) {
    TILE_FULL(0); TILE_FULL(1); TILE_FULL(2); TILE_FULL(3);
  }

  // peeled tail t = 128..131 (ring slots 0..3)
  { READS(0); STAGE4(131, 3); MFMA32; VMW8; BAR; SCHED0; }  // t=128
  { READS(1); MFMA32; VMW4; BAR; SCHED0; }                  // t=129
  { READS(2); MFMA32; VMW0; BAR; SCHED0; }                  // t=130
  { READS(3); MFMA32; }                                     // t=131

  // epilogue: + bias, fp32 store. C/D: col = lane&15, row = (lane>>4)*4 + reg
#pragma unroll
  for (int ni = 0; ni < 4; ++ni) {
    int n = n0 + wn + ni * 16 + ln15;
    float bz = bias[n];
#pragma unroll
    for (int mi = 0; mi < 8; ++mi) {
      f32x4 v = acc[mi][ni];
      int mb = m0 + wm + mi * 16 + ln4 * 4;
#pragma unroll
      for (int jj = 0; jj < 4; ++jj)
        out[(size_t)(mb + jj) * N_TOT + n] = v[jj] + bz;
    }
  }
}

// ---------------- fallback GEMM (reg-staged f32->f16, 128x128, low ws)
__global__ __launch_bounds__(256) void gemm_fallback(
    const float* __restrict__ x, const float* __restrict__ wgt,
    const float* __restrict__ midw, const float* __restrict__ lorabf,
    const float* __restrict__ bias, float* __restrict__ out) {
  __shared__ _Float16 As[128 * 64];
  __shared__ _Float16 Bs[128 * 64];
  int tid = threadIdx.x, lane = tid & 63, w = tid >> 6;
  int mt = blockIdx.x & 63, nt = blockIdx.x >> 6;
  int m0 = mt << 7, n0 = nt << 7;
  int wm = (w >> 1) * 64, wn = (w & 1) * 64;
  f32x4 acc[4][4] = {};
  for (int ks = 0; ks < 66; ++ks) {
    int k0 = ks * 64;
    const float *asrc, *bsrc; size_t astr, bstr; int ac, bc;
    if (ks < 64) { asrc = x;    astr = K_IN; ac = k0;        bsrc = wgt;    bstr = K_IN; bc = k0; }
    else         { asrc = midw; astr = 128;  ac = k0 - K_IN; bsrc = lorabf; bstr = 128;  bc = k0 - K_IN; }
#pragma unroll
    for (int it = 0; it < 8; ++it) {
      int idx = tid + it * 256;
      int r = idx >> 4, c4 = idx & 15;
      float4 fa = *(const float4*)(asrc + (size_t)(m0 + r) * astr + ac + c4 * 4);
      cvt_store4(As + r * 64 + c4 * 4, fa);
      float4 fb = *(const float4*)(bsrc + (size_t)(n0 + r) * bstr + bc + c4 * 4);
      cvt_store4(Bs + r * 64 + c4 * 4, fb);
    }
    __syncthreads();
#pragma unroll
    for (int kk = 0; kk < 2; ++kk) {
      half8 a[4], bf[4];
#pragma unroll
      for (int mi = 0; mi < 4; ++mi)
        a[mi] = *(const half8*)(As + (wm + mi * 16 + (lane & 15)) * 64 + kk * 32 + (lane >> 4) * 8);
#pragma unroll
      for (int ni = 0; ni < 4; ++ni)
        bf[ni] = *(const half8*)(Bs + (wn + ni * 16 + (lane & 15)) * 64 + kk * 32 + (lane >> 4) * 8);
#pragma unroll
      for (int mi = 0; mi < 4; ++mi)
#pragma unroll
        for (int ni = 0; ni < 4; ++ni)
          acc[mi][ni] = __builtin_amdgcn_mfma_f32_16x16x32_f16(a[mi], bf[ni], acc[mi][ni], 0, 0, 0);
    }
    __syncthreads();
  }
#pragma unroll
  for (int ni = 0; ni < 4; ++ni) {
    int n = n0 + wn + ni * 16 + (lane & 15);
    float bz = bias[n];
#pragma unroll
    for (int mi = 0; mi < 4; ++mi) {
      f32x4 v = acc[mi][ni];
      int mbase = m0 + wm + mi * 16 + (lane >> 4) * 4;
#pragma unroll
      for (int jj = 0; jj < 4; ++jj)
        out[(size_t)(mbase + jj) * N_TOT + n] = v[jj] + bz;
    }
  }
}

extern "C" void kernel_launch(void* const* d_in, const int* in_sizes, int n_in,
                              void* d_out, int out_size, void* d_ws, size_t ws_size,
                              hipStream_t stream) {
  const float* x      = (const float*)d_in[0];
  const float* router = (const float*)d_in[1];
  const float* wgt    = (const float*)d_in[2];
  const float* bias   = (const float*)d_in[3];
  const float* loraA  = (const float*)d_in[4];
  const float* loraB  = (const float*)d_in[5];
  float* out = (float*)d_out;
  char* ws = (char*)d_ws;

  const size_t XAUG_B = (size_t)M_TOT * KA * 2;    // 69,206,016
  const size_t WAUG_B = (size_t)N_TOT * KA * 2;    // 34,603,008
  const size_t LAH_B  = (size_t)128 * K_IN * 2;    //  1,048,576
  const size_t MIDW_B = (size_t)M_TOT * 128 * 4;   //  4,194,304
  bool fast = ws_size >= XAUG_B + WAUG_B + LAH_B;

  if (fast) {
    _Float16* Xa  = (_Float16*)ws;
    _Float16* Wa  = (_Float16*)(ws + XAUG_B);
    _Float16* lAh = (_Float16*)(ws + XAUG_B + WAUG_B);
    prep_all<<<3360, 256, 0, stream>>>(x, wgt, loraA, loraB, Xa, Wa, lAh);
    mid2r_kernel<<<256, 256, 0, stream>>>(Xa, lAh, router);
    gemm256<<<512, 512, 0, stream>>>(Xa, Wa, bias, out);
  } else {
    float* midw   = (float*)ws;
    float* lorabf = (float*)(ws + MIDW_B);
    lorabf_gather_f32<<<2048, 256, 0, stream>>>(loraB, lorabf);
    mid_kernel<<<256, 256, 0, stream>>>(x, loraA, router, midw);
    gemm_fallback<<<2048, 256, 0, stream>>>(x, wgt, midw, lorabf, bias, out);
  }
}